// Round 16
// baseline (45.343 us; speedup 1.0000x reference)
//
#include <hip/hip_runtime.h>

#define NWIDTH 299592
#define NOUT   51360

typedef unsigned long long ull;
typedef unsigned short u16;

// Lyndon combinatorics (Witt formula; validated by rounds 8-15 passes):
__device__ const int g_B2[8] = {8, 15, 21, 26, 30, 33, 35, 36};
__device__ const int g_B3[8] = {36, 92, 134, 164, 184, 196, 202, 204};
__device__ const int g_B4[8] = {204, 624, 897, 1062, 1152, 1194, 1209, 1212};
__device__ const int g_B5[8] = {1212, 4404, 6210, 7140, 7560, 7716, 7758, 7764};
__device__ const int g_C6[8] = {0, 24052, 35861, 41016, 42926, 43480, 43587, 43596};

__device__ __forceinline__ bool is_lyndon6(unsigned p) {
  const unsigned mask = (1u << 18) - 1u;
#pragma unroll
  for (int k = 1; k < 6; ++k) {
    unsigned rot = ((p << (3 * k)) & mask) | (p >> (18 - 3 * k));
    if (p >= rot) return false;
  }
  return true;
}
__device__ __forceinline__ bool is_lyndon(unsigned p, int n) {
  const unsigned nb = 3u * (unsigned)n;
  const unsigned mask = (1u << nb) - 1u;
  for (int k = 1; k < n; ++k) {
    unsigned rot = ((p << (3 * k)) & mask) | (p >> (nb - 3 * k));
    if (p >= rot) return false;
  }
  return true;
}

// ---- prep: pos16[global_rank] = 15-bit position within the j1 slice ----
__global__ __launch_bounds__(1024) void lyndon_prep(u16* __restrict__ pos16) {
  __shared__ int wsum[16];
  const int tid = threadIdx.x, lane = tid & 63, wv = tid >> 6;
  const int j = blockIdx.x;
  const unsigned pb = ((unsigned)j << 15) | ((unsigned)tid << 5);
  unsigned lm = 0;
  int c = 0;
  for (int i = 0; i < 32; ++i)
    if (is_lyndon6(pb | (unsigned)i)) { lm |= 1u << i; ++c; }
  int pref = c;
  for (int d = 1; d < 64; d <<= 1) { int t = __shfl_up(pref, d); if (lane >= d) pref += t; }
  if (lane == 63) wsum[wv] = pref;
  __syncthreads();
  int base = 0;
  for (int i = 0; i < wv; ++i) base += wsum[i];
  int ex = g_C6[j] + base + pref - c;
  unsigned m = lm;
  const int p0 = tid << 5;
  while (m) {
    const int bit = __builtin_ctz(m);
    pos16[ex++] = (u16)(p0 + bit);
    m &= m - 1;
  }
}

// ---- algebra kernel LDS (floats): 6448 = 25.8 KiB ----
#define L_S3  0       // 512
#define L_S2  512     // 64
#define L_S1  576     // 8
#define L_PA  584     // 584
#define L_PB  1168    // 584
#define L_A2  1752    // 8
#define L_A3  1760    // 64
#define L_A4  1824    // 512
#define L_W4  2336    // 8 int
#define L_W5  2344    // 8 int
#define L_A5  2352    // 4096
#define L_TOT 6448

// Kernel A: 448 = 8 XCD x 8 batch x 7 j1. Horner -> A2..A5; writes Aws (j1<4)
// for the eval kernel; emits levels 1..5 outputs + sparse L6 (j1 in {4,5,6}).
__global__ __launch_bounds__(512)
void logsig_algebra(const float* __restrict__ sig,
                    const u16* __restrict__ pos16,
                    float* __restrict__ Aws,
                    float* __restrict__ out) {
  __shared__ __align__(16) float sm[L_TOT];
  int* W4i = (int*)(sm + L_W4);
  int* W5i = (int*)(sm + L_W5);

  const int tid = threadIdx.x, lane = tid & 63, wv = tid >> 6;
  const int bid = blockIdx.x;
  const int xcd = bid & 7;
  const int g   = bid >> 3;            // 0..55
  const int b   = xcd * 8 + g / 7;
  const int j1  = g % 7;

  const float* __restrict__ S   = sig + (size_t)b * NWIDTH;
  const float* __restrict__ S4g = S + 584;
  const float* __restrict__ S5g = S + 4680;
  const float* __restrict__ S6j = S + 37448 + (size_t)j1 * 32768;
  float* __restrict__ outb = out + (size_t)b * NOUT;

  const float p1 = S[j1];
  const float c2p1 = -0.5f * p1;
  const int q4 = tid << 2;

  // ---- stage ----
  sm[L_S3 + tid] = S[72 + tid];
  if (tid < 64) sm[L_S2 + tid] = S[8 + tid];
  if (tid < 8)  sm[L_S1 + tid] = S[tid];
  if (tid < 8)  sm[L_PA + tid]      = S[8 + j1 * 8 + tid];
  if (tid < 64) sm[L_PA + 8 + tid]  = S[72 + j1 * 64 + tid];
  sm[L_PA + 72 + tid] = S4g[j1 * 512 + tid];
  float p5[8];
  {
    float4 va = *(const float4*)(S5g + j1 * 4096 + q4);
    float4 vb = *(const float4*)(S5g + j1 * 4096 + 2048 + q4);
    p5[0] = va.x; p5[1] = va.y; p5[2] = va.z; p5[3] = va.w;
    p5[4] = vb.x; p5[5] = vb.y; p5[6] = vb.z; p5[7] = vb.w;
  }
  float a5[8] = {0.f, 0.f, 0.f, 0.f, 0.f, 0.f, 0.f, 0.f};
  float a4 = 0.f, a3 = 0.f, a2 = 0.f;

  // ---- gather flags for levels 4,5 (overlaps staging) ----
  ull m4 = 0;
  unsigned fm5a = 0, fm5b = 0;
  int exA = 0, exB = 0;
  {
    bool f4 = is_lyndon(((unsigned)j1 << 9) | (unsigned)tid, 4);
    m4 = __ballot(f4);
    if (lane == 0) W4i[wv] = __popcll(m4);
    int c5a = 0, c5b = 0;
#pragma unroll
    for (int e = 0; e < 4; ++e) {
      if (is_lyndon(((unsigned)j1 << 12) | (unsigned)(q4 + e), 5)) { fm5a |= 1u << e; ++c5a; }
      if (is_lyndon(((unsigned)j1 << 12) | (unsigned)(2048 + q4 + e), 5)) { fm5b |= 1u << e; ++c5b; }
    }
    int prefpk = c5a | (c5b << 16);
    for (int d = 1; d < 64; d <<= 1) { int t = __shfl_up(prefpk, d); if (lane >= d) prefpk += t; }
    if (lane == 63) W5i[wv] = prefpk;
    exA = (prefpk & 0xffff) - c5a;
    exB = (prefpk >> 16) - c5b;
  }
  __syncthreads();

  const float s1t = sm[L_S1 + (tid & 7)];
  float s1q4[4];
#pragma unroll
  for (int e = 0; e < 4; ++e) s1q4[e] = sm[L_S1 + ((tid & 1) << 2) + e];

  // ---- Horner n=2..5 (2x4 tiling) ----
  const float coefs[7] = {0.f, 0.f, -0.5f, 1.f / 3.f, -0.25f, 0.2f, -1.f / 6.f};
#pragma unroll
  for (int n = 2; n <= 5; ++n) {
    const float coef = coefs[n];
    const int RP = (n & 1) ? L_PB : L_PA;
    const int WP = (n & 1) ? L_PA : L_PB;
    a4 += coef * sm[RP + 72 + tid];
    if (tid < 64) a3 += coef * sm[RP + 8 + tid];
    if (tid < 8)  a2 += coef * sm[RP + tid];
    float t4 = sm[RP + 8 + (tid >> 3)] * s1t
             + sm[RP + (tid >> 6)] * sm[L_S2 + (tid & 63)];
    if (n == 2) t4 += p1 * sm[L_S3 + tid];
    float t3 = 0.f, t2 = 0.f;
    if (tid < 64) {
      t3 = sm[RP + (tid >> 3)] * s1t;
      if (n == 2) t3 += p1 * sm[L_S2 + tid];
    }
    if (tid < 8 && n == 2) t2 = p1 * s1t;
    {
      const float rp4a = sm[RP + 72 + (tid >> 1)];
      const float rp4b = sm[RP + 72 + 256 + (tid >> 1)];
      const float rp3a = sm[RP + 8 + (tid >> 4)];
      const float rp3b = sm[RP + 8 + 32 + (tid >> 4)];
      const float rp2a = sm[RP + (tid >> 7)];
      const float rp2b = sm[RP + 4 + (tid >> 7)];
      const float4 s2v = *(const float4*)(sm + L_S2 + (q4 & 63));
      const float4 s3v = *(const float4*)(sm + L_S3 + (q4 & 511));
      const float s2q[4] = {s2v.x, s2v.y, s2v.z, s2v.w};
      const float s3q[4] = {s3v.x, s3v.y, s3v.z, s3v.w};
#pragma unroll
      for (int e = 0; e < 4; ++e) {
        a5[e]     += coef * p5[e];
        a5[4 + e] += coef * p5[4 + e];
        p5[e]     = rp4a * s1q4[e] + rp3a * s2q[e] + rp2a * s3q[e];
        p5[4 + e] = rp4b * s1q4[e] + rp3b * s2q[e] + rp2b * s3q[e];
      }
      if (n == 2) {
        const float4 s4va = *(const float4*)(S4g + q4);
        const float4 s4vb = *(const float4*)(S4g + 2048 + q4);
        const float s4qa[4] = {s4va.x, s4va.y, s4va.z, s4va.w};
        const float s4qb[4] = {s4vb.x, s4vb.y, s4vb.z, s4vb.w};
#pragma unroll
        for (int e = 0; e < 4; ++e) {
          p5[e] += p1 * s4qa[e];
          p5[4 + e] += p1 * s4qb[e];
        }
      }
    }
    sm[WP + 72 + tid] = t4;
    if (tid < 64) sm[WP + 8 + tid] = t3;
    if (tid < 8)  sm[WP + tid]     = t2;
    __syncthreads();
  }
#pragma unroll
  for (int e = 0; e < 8; ++e) a5[e] += coefs[6] * p5[e];   // n=6 (level 5 only)

  // ---- A dump (LDS + workspace for the eval kernel) ----
  sm[L_A4 + tid] = a4;
  if (tid < 64) sm[L_A3 + tid] = a3;
  if (tid < 8)  sm[L_A2 + tid] = a2;
  *(float4*)(sm + L_A5 + q4)        = make_float4(a5[0], a5[1], a5[2], a5[3]);
  *(float4*)(sm + L_A5 + 2048 + q4) = make_float4(a5[4], a5[5], a5[6], a5[7]);
  if (j1 < 4) {
    float* Aw = Aws + (size_t)((b << 2) + j1) * 4680;
    if (tid < 8)  Aw[tid] = a2;
    if (tid < 64) Aw[8 + tid] = a3;
    Aw[72 + tid] = a4;
    *(float4*)(Aw + 584 + q4)        = make_float4(a5[0], a5[1], a5[2], a5[3]);
    *(float4*)(Aw + 584 + 2048 + q4) = make_float4(a5[4], a5[5], a5[6], a5[7]);
  }
  __syncthreads();

  // ---- closed-form L2..L5 + emit ----
  float l2v = 0.f, l3v = 0.f;
  if (tid < 8)
    l2v = sm[L_S2 + j1 * 8 + tid] + c2p1 * s1t;
  if (tid < 64)
    l3v = sm[L_S3 + j1 * 64 + tid] + sm[L_A2 + (tid >> 3)] * s1t
        + c2p1 * sm[L_S2 + tid];
  const float l4v = S4g[j1 * 512 + tid] + sm[L_A3 + (tid >> 3)] * s1t
                  + sm[L_A2 + (tid >> 6)] * sm[L_S2 + (tid & 63)]
                  + c2p1 * sm[L_S3 + tid];
  float l5a[4], l5b[4];
  {
    const float4 via  = *(const float4*)(S5g + j1 * 4096 + q4);
    const float4 vib  = *(const float4*)(S5g + j1 * 4096 + 2048 + q4);
    const float4 s4va = *(const float4*)(S4g + q4);
    const float4 s4vb = *(const float4*)(S4g + 2048 + q4);
    const float4 s2v  = *(const float4*)(sm + L_S2 + (q4 & 63));
    const float4 s3v  = *(const float4*)(sm + L_S3 + (q4 & 511));
    const float l5ia[4] = {via.x, via.y, via.z, via.w};
    const float l5ib[4] = {vib.x, vib.y, vib.z, vib.w};
    const float s4qa[4] = {s4va.x, s4va.y, s4va.z, s4va.w};
    const float s4qb[4] = {s4vb.x, s4vb.y, s4vb.z, s4vb.w};
    const float s2q[4]  = {s2v.x, s2v.y, s2v.z, s2v.w};
    const float s3q[4]  = {s3v.x, s3v.y, s3v.z, s3v.w};
    const float a4a = sm[L_A4 + (tid >> 1)],  a4b = sm[L_A4 + 256 + (tid >> 1)];
    const float a3a = sm[L_A3 + (tid >> 4)],  a3b = sm[L_A3 + 32 + (tid >> 4)];
    const float a2a = sm[L_A2 + (tid >> 7)],  a2b = sm[L_A2 + 4 + (tid >> 7)];
#pragma unroll
    for (int e = 0; e < 4; ++e) {
      l5a[e] = l5ia[e] + a4a * s1q4[e] + a3a * s2q[e] + a2a * s3q[e] + c2p1 * s4qa[e];
      l5b[e] = l5ib[e] + a4b * s1q4[e] + a3b * s2q[e] + a2b * s3q[e] + c2p1 * s4qb[e];
    }
  }
  if (tid == 0) {
    outb[j1] = p1;
    if (j1 == 0) outb[7] = sm[L_S1 + 7];
  }
  if (tid < 8 && tid > j1) outb[g_B2[j1] + tid - j1 - 1] = l2v;
  if (tid < 64) {
    bool f3 = is_lyndon(((unsigned)j1 << 6) | (unsigned)tid, 3);
    ull m3 = __ballot(f3);
    if (f3) outb[g_B3[j1] + __popcll(m3 & ((1ull << lane) - 1ull))] = l3v;
  }
  {
    int base = 0;
    for (int i = 0; i < wv; ++i) base += W4i[i];
    if ((m4 >> lane) & 1ull)
      outb[g_B4[j1] + base + __popcll(m4 & ((1ull << lane) - 1ull))] = l4v;
  }
  {
    int baseA = 0, baseB = 0, totalA = 0;
#pragma unroll
    for (int i = 0; i < 8; ++i) {
      int w = W5i[i];
      totalA += w & 0xffff;
      if (i < wv) { baseA += w & 0xffff; baseB += w >> 16; }
    }
    int slotA = g_B5[j1] + baseA + exA;
    int slotB = g_B5[j1] + totalA + baseB + exB;
#pragma unroll
    for (int e = 0; e < 4; ++e)
      if ((fm5a >> e) & 1u) outb[slotA++] = l5a[e];
#pragma unroll
    for (int e = 0; e < 4; ++e)
      if ((fm5b >> e) & 1u) outb[slotB++] = l5b[e];
  }

  // ---- sparse level 6 (j1 in {4,5,6}): direct pos16-driven eval ----
  if (j1 >= 4) {
    const int r0 = g_C6[j1];
    const int cnt = g_C6[j1 + 1] - r0;
    for (int i = tid; i < cnt; i += 512) {
      const int pl = pos16[r0 + i];
      float v = S6j[pl]
              + sm[L_A5 + (pl >> 3)] * sm[L_S1 + (pl & 7)]
              + sm[L_A4 + (pl >> 6)] * sm[L_S2 + (pl & 63)]
              + sm[L_A3 + (pl >> 9)] * sm[L_S3 + (pl & 511)]
              + sm[L_A2 + (pl >> 12)] * S4g[pl & 4095]
              + c2p1 * S5g[pl];
      outb[7764 + r0 + i] = v;
    }
  }
}

// Kernel B: dense level-6 eval. 2048 = 8 XCD x 8 batch x 32 rank-chunks.
// Zero LDS, zero barriers: every thread is an independent rank->value map with
// 10 independent loads per eval -> latency hidden purely by occupancy (32 w/CU).
__global__ __launch_bounds__(256)
void logsig_eval6(const float* __restrict__ sig,
                  const float* __restrict__ Aws,
                  const u16* __restrict__ pos16,
                  float* __restrict__ out) {
  const int bid = blockIdx.x;
  const int xcd = bid & 7;
  const int g   = bid >> 3;            // 0..255
  const int b   = xcd * 8 + (g >> 5);
  const int chunk = g & 31;
  const int r0 = chunk * 1342;
  const int r1 = (r0 + 1342 < 42926) ? r0 + 1342 : 42926;

  const float* __restrict__ S = sig + (size_t)b * NWIDTH;
  float* __restrict__ outr = out + (size_t)b * NOUT + 7764;

  for (int r = r0 + threadIdx.x; r < r1; r += 256) {
    const int pl = pos16[r];
    const int j1 = (r >= 24052) + (r >= 35861) + (r >= 41016);
    const float* __restrict__ Aw = Aws + (size_t)((b << 2) + j1) * 4680;
    const float* __restrict__ S6j = S + 37448 + (j1 << 15);
    float v = S6j[pl]
            + Aw[584 + (pl >> 3)] * S[pl & 7]
            + Aw[72 + (pl >> 6)] * S[8 + (pl & 63)]
            + Aw[8 + (pl >> 9)] * S[72 + (pl & 511)]
            + Aw[pl >> 12] * S[584 + (pl & 4095)]
            + (-0.5f * S[j1]) * S[4680 + pl];
    outr[r] = v;
  }
}

// ---------- launch ----------
// d_ws: Aws[64*4*4680] float (4.79 MB, 16B-aligned) | pos16[43596] u16 (85 KB)

extern "C" void kernel_launch(void* const* d_in, const int* in_sizes, int n_in,
                              void* d_out, int out_size, void* d_ws, size_t ws_size,
                              hipStream_t stream) {
  const float* sig = (const float*)d_in[0];
  float* out = (float*)d_out;
  float* Aws = (float*)d_ws;                       // 64*4*4680 floats
  u16* pos16 = (u16*)(Aws + 64 * 4 * 4680);        // 43596 u16

  lyndon_prep<<<7, 1024, 0, stream>>>(pos16);
  logsig_algebra<<<448, 512, 0, stream>>>(sig, pos16, Aws, out);
  logsig_eval6<<<2048, 256, 0, stream>>>(sig, Aws, pos16, out);
}

// Round 17
// 40.354 us; speedup vs baseline: 1.1236x; 1.1236x over previous
//
#include <hip/hip_runtime.h>

#define NWIDTH 299592
#define NOUT   51360

typedef unsigned long long ull;
typedef unsigned short u16;

// Lyndon combinatorics (Witt formula; validated by rounds 8-16 passes):
__device__ const int g_B2[8] = {8, 15, 21, 26, 30, 33, 35, 36};
__device__ const int g_B3[8] = {36, 92, 134, 164, 184, 196, 202, 204};
__device__ const int g_B4[8] = {204, 624, 897, 1062, 1152, 1194, 1209, 1212};
__device__ const int g_B5[8] = {1212, 4404, 6210, 7140, 7560, 7716, 7758, 7764};
__device__ const int g_C6[8] = {0, 24052, 35861, 41016, 42926, 43480, 43587, 43596};
// 16 balanced units per batch: j1 counts {6,4,2,1,1,1,1}; first unit of each
// j1 group also emits the algebra (levels 1..5) outputs.
__device__ const int g_uj1[16] = {0,0,0,0,0,0, 1,1,1,1, 2,2, 3, 4, 5, 6};
__device__ const int g_ur0[16] = {0, 4009, 8018, 12027, 16036, 20044,
                                  24052, 27005, 29957, 32909,
                                  35861, 38439, 41016, 42926, 43480, 43587};
__device__ const int g_ur1[16] = {4009, 8018, 12027, 16036, 20044, 24052,
                                  27005, 29957, 32909, 35861,
                                  38439, 41016, 42926, 43480, 43587, 43596};
__device__ const int g_ualg[16] = {1,0,0,0,0,0, 1,0,0,0, 1,0, 1, 1, 1, 1};

__device__ __forceinline__ bool is_lyndon6(unsigned p) {
  const unsigned mask = (1u << 18) - 1u;
#pragma unroll
  for (int k = 1; k < 6; ++k) {
    unsigned rot = ((p << (3 * k)) & mask) | (p >> (18 - 3 * k));
    if (p >= rot) return false;
  }
  return true;
}
__device__ __forceinline__ bool is_lyndon(unsigned p, int n) {
  const unsigned nb = 3u * (unsigned)n;
  const unsigned mask = (1u << nb) - 1u;
  for (int k = 1; k < n; ++k) {
    unsigned rot = ((p << (3 * k)) & mask) | (p >> (nb - 3 * k));
    if (p >= rot) return false;
  }
  return true;
}

// ---- prep: pos16[global_rank] = 15-bit position within the j1 slice ----
__global__ __launch_bounds__(1024) void lyndon_prep(u16* __restrict__ pos16) {
  __shared__ int wsum[16];
  const int tid = threadIdx.x, lane = tid & 63, wv = tid >> 6;
  const int j = blockIdx.x;
  const unsigned pb = ((unsigned)j << 15) | ((unsigned)tid << 5);
  unsigned lm = 0;
  int c = 0;
  for (int i = 0; i < 32; ++i)
    if (is_lyndon6(pb | (unsigned)i)) { lm |= 1u << i; ++c; }
  int pref = c;
  for (int d = 1; d < 64; d <<= 1) { int t = __shfl_up(pref, d); if (lane >= d) pref += t; }
  if (lane == 63) wsum[wv] = pref;
  __syncthreads();
  int base = 0;
  for (int i = 0; i < wv; ++i) base += wsum[i];
  int ex = g_C6[j] + base + pref - c;
  unsigned m = lm;
  const int p0 = tid << 5;
  while (m) {
    const int bit = __builtin_ctz(m);
    pos16[ex++] = (u16)(p0 + bit);
    m &= m - 1;
  }
}

// ---- main LDS layout (floats): 7872 = 31.5 KiB -> 4 blocks/CU ----
#define L_S3  0       // 512
#define L_S2  512     // 64
#define L_S1  576     // 8
#define L_A2  584     // 8
#define L_A3  592     // 64
#define L_A4  656     // 512
#define L_W2  1168    // 8
#define L_W3  1176    // 64
#define L_W4  1240    // 512
#define L_W4i 1752    // 8 int
#define L_W5i 1760    // 8 int
#define L_A5  1768    // 4096 (16B aligned: 1768*4 % 16 == 0)
#define L_PL  5864    // u16[4016] = 2008 floats
#define L_TOT 7872

// grid 1024 = 8 XCD x 8 batch x 16 units. CLOSED-FORM algebra (no Horner
// recursion, no LDS ping-pong): A2..A4 and coefficient-shifted W2..W4 are
// direct polynomials in the staged S-values; A5[q] = c2*S5[j1 q] +
// W4[q>>3]*S1 + W3[q>>6]*S2 + W2[q>>9]*S3 + c3*p1*S4[q]. Verified
// term-by-term against the round-8..16 Horner accumulation. 3 barriers total.
__global__ __launch_bounds__(512)
void logsig_fused(const float* __restrict__ sig,
                  const u16* __restrict__ pos16,
                  float* __restrict__ out) {
  __shared__ __align__(16) float sm[L_TOT];
  int* W4i = (int*)(sm + L_W4i);
  int* W5i = (int*)(sm + L_W5i);
  u16* PL  = (u16*)(sm + L_PL);

  const int tid = threadIdx.x, lane = tid & 63, wv = tid >> 6;
  const int bid = blockIdx.x;
  const int xcd = bid & 7;
  const int rr  = bid >> 3;            // 0..127
  const int b   = xcd * 8 + (rr >> 4);
  const int u   = rr & 15;
  const int j1  = g_uj1[u];
  const bool isalg = g_ualg[u] != 0;
  const int r0 = g_ur0[u], r1 = g_ur1[u];
  const int cnt = r1 - r0;

  const float* __restrict__ S   = sig + (size_t)b * NWIDTH;
  const float* __restrict__ S4g = S + 584;
  const float* __restrict__ S5g = S + 4680;
  const float* __restrict__ S6j = S + 37448 + (size_t)j1 * 32768;
  float* __restrict__ outb = out + (size_t)b * NOUT;

  const float p1 = S[j1];
  const float c2 = -0.5f, c3 = 1.f / 3.f, c4 = -0.25f, c5 = 0.2f, c6 = -1.f / 6.f;
  const float c2p1 = c2 * p1;
  const float c3p1 = c3 * p1;
  const int q4 = tid << 2;

  // ---- stage ----
  sm[L_S3 + tid] = S[72 + tid];
  if (tid < 64) sm[L_S2 + tid] = S[8 + tid];
  if (tid < 8)  sm[L_S1 + tid] = S[tid];
  for (int i = tid; i < cnt; i += 512) PL[i] = pos16[r0 + i];   // prefetch ranks
  const float s4p = S4g[j1 * 512 + tid];        // S4[j1 | x=tid] (coalesced)
  float p5[8];                                  // S5[j1 | q], 2x4 halves
  {
    float4 va = *(const float4*)(S5g + j1 * 4096 + q4);
    float4 vb = *(const float4*)(S5g + j1 * 4096 + 2048 + q4);
    p5[0] = va.x; p5[1] = va.y; p5[2] = va.z; p5[3] = va.w;
    p5[4] = vb.x; p5[5] = vb.y; p5[6] = vb.z; p5[7] = vb.w;
  }
  float4 s4qa, s4qb;                            // S4[q] for the 2 halves
  s4qa = *(const float4*)(S4g + q4);
  s4qb = *(const float4*)(S4g + 2048 + q4);

  // ---- gather flags for levels 4,5 (overlaps staging) ----
  ull m4 = 0;
  unsigned fm5a = 0, fm5b = 0;
  int exA = 0, exB = 0;
  if (isalg) {
    bool f4 = is_lyndon(((unsigned)j1 << 9) | (unsigned)tid, 4);
    m4 = __ballot(f4);
    if (lane == 0) W4i[wv] = __popcll(m4);
    int c5a = 0, c5b = 0;
#pragma unroll
    for (int e = 0; e < 4; ++e) {
      if (is_lyndon(((unsigned)j1 << 12) | (unsigned)(q4 + e), 5)) { fm5a |= 1u << e; ++c5a; }
      if (is_lyndon(((unsigned)j1 << 12) | (unsigned)(2048 + q4 + e), 5)) { fm5b |= 1u << e; ++c5b; }
    }
    int prefpk = c5a | (c5b << 16);
    for (int d = 1; d < 64; d <<= 1) { int t = __shfl_up(prefpk, d); if (lane >= d) prefpk += t; }
    if (lane == 63) W5i[wv] = prefpk;
    exA = (prefpk & 0xffff) - c5a;
    exB = (prefpk >> 16) - c5b;
  }
  __syncthreads();   // barrier 1: S-caches + PL visible

  // ---- closed-form A2..A4 / W2..W4 ----
  {
    const int x = tid;                               // 3-letter suffix j2j3j4
    const float s1_4 = sm[L_S1 + (x & 7)];
    const float s1_3 = sm[L_S1 + ((x >> 3) & 7)];
    const float s1_2 = sm[L_S1 + (x >> 6)];
    const float s3p  = sm[L_S3 + j1 * 64 + (x >> 3)];   // S3[j1 j2 j3]
    const float s2p  = sm[L_S2 + j1 * 8 + (x >> 6)];    // S2[j1 j2]
    const float w4_2 = s3p * s1_4 + s2p * sm[L_S2 + (x & 63)] + p1 * sm[L_S3 + x];
    const float w4_3 = (s2p * s1_3 + p1 * sm[L_S2 + (x >> 3)]) * s1_4
                     + p1 * s1_2 * sm[L_S2 + (x & 63)];
    const float w4_4 = p1 * s1_2 * s1_3 * s1_4;
    sm[L_A4 + x] = c2 * s4p + c3 * w4_2 + c4 * w4_3 + c5 * w4_4;
    sm[L_W4 + x] = c3 * s4p + c4 * w4_2 + c5 * w4_3 + c6 * w4_4;
  }
  if (tid < 64) {
    const int y = tid;                               // j2j3
    const float w3_2 = sm[L_S2 + j1 * 8 + (y >> 3)] * sm[L_S1 + (y & 7)]
                     + p1 * sm[L_S2 + y];
    const float w3_3 = p1 * sm[L_S1 + (y >> 3)] * sm[L_S1 + (y & 7)];
    const float s3py = sm[L_S3 + j1 * 64 + y];
    sm[L_A3 + y] = c2 * s3py + c3 * w3_2 + c4 * w3_3;
    sm[L_W3 + y] = c3 * s3py + c4 * w3_2 + c5 * w3_3;
  }
  if (tid < 8) {
    const int z = tid;
    const float s2pz = sm[L_S2 + j1 * 8 + z];
    const float s1z  = sm[L_S1 + z];
    sm[L_A2 + z] = c2 * s2pz + c3 * p1 * s1z;
    sm[L_W2 + z] = c3 * s2pz + c4 * p1 * s1z;
  }
  __syncthreads();   // barrier 2: A2..A4 / W2..W4 visible

  const float s1t = sm[L_S1 + (tid & 7)];
  float s1q4[4];
#pragma unroll
  for (int e = 0; e < 4; ++e) s1q4[e] = sm[L_S1 + ((tid & 1) << 2) + e];

  // ---- A5 (to LDS) + L5 (regs), 2x4 halves ----
  float l5a[4], l5b[4];
  {
    const float W4a = sm[L_W4 + (tid >> 1)],       W4b = sm[L_W4 + 256 + (tid >> 1)];
    const float A4a = sm[L_A4 + (tid >> 1)],       A4b = sm[L_A4 + 256 + (tid >> 1)];
    const float W3a = sm[L_W3 + (tid >> 4)],       W3b = sm[L_W3 + 32 + (tid >> 4)];
    const float A3a = sm[L_A3 + (tid >> 4)],       A3b = sm[L_A3 + 32 + (tid >> 4)];
    const float W2a = sm[L_W2 + (tid >> 7)],       W2b = sm[L_W2 + 4 + (tid >> 7)];
    const float A2a = sm[L_A2 + (tid >> 7)],       A2b = sm[L_A2 + 4 + (tid >> 7)];
    const float4 s2v = *(const float4*)(sm + L_S2 + (q4 & 63));
    const float4 s3v = *(const float4*)(sm + L_S3 + (q4 & 511));
    const float s2q[4] = {s2v.x, s2v.y, s2v.z, s2v.w};
    const float s3q[4] = {s3v.x, s3v.y, s3v.z, s3v.w};
    const float s4a[4] = {s4qa.x, s4qa.y, s4qa.z, s4qa.w};
    const float s4b[4] = {s4qb.x, s4qb.y, s4qb.z, s4qb.w};
    float a5A[4], a5B[4];
#pragma unroll
    for (int e = 0; e < 4; ++e) {
      a5A[e] = c2 * p5[e]     + W4a * s1q4[e] + W3a * s2q[e] + W2a * s3q[e] + c3p1 * s4a[e];
      a5B[e] = c2 * p5[4 + e] + W4b * s1q4[e] + W3b * s2q[e] + W2b * s3q[e] + c3p1 * s4b[e];
      l5a[e] = p5[e]     + A4a * s1q4[e] + A3a * s2q[e] + A2a * s3q[e] + c2p1 * s4a[e];
      l5b[e] = p5[4 + e] + A4b * s1q4[e] + A3b * s2q[e] + A2b * s3q[e] + c2p1 * s4b[e];
    }
    *(float4*)(sm + L_A5 + q4)        = make_float4(a5A[0], a5A[1], a5A[2], a5A[3]);
    *(float4*)(sm + L_A5 + 2048 + q4) = make_float4(a5B[0], a5B[1], a5B[2], a5B[3]);
  }

  if (isalg) {
    // ---- closed-form L2..L4 + emit levels 1..5 ----
    float l2v = 0.f, l3v = 0.f;
    if (tid < 8)
      l2v = sm[L_S2 + j1 * 8 + tid] + c2p1 * s1t;
    if (tid < 64)
      l3v = sm[L_S3 + j1 * 64 + tid] + sm[L_A2 + (tid >> 3)] * s1t
          + c2p1 * sm[L_S2 + tid];
    const float l4v = s4p + sm[L_A3 + (tid >> 3)] * s1t
                    + sm[L_A2 + (tid >> 6)] * sm[L_S2 + (tid & 63)]
                    + c2p1 * sm[L_S3 + tid];
    if (tid == 0) {
      outb[j1] = p1;
      if (j1 == 0) outb[7] = sm[L_S1 + 7];
    }
    if (tid < 8 && tid > j1) outb[g_B2[j1] + tid - j1 - 1] = l2v;
    if (tid < 64) {
      bool f3 = is_lyndon(((unsigned)j1 << 6) | (unsigned)tid, 3);
      ull m3 = __ballot(f3);
      if (f3) outb[g_B3[j1] + __popcll(m3 & ((1ull << lane) - 1ull))] = l3v;
    }
    {
      int base = 0;
      for (int i = 0; i < wv; ++i) base += W4i[i];
      if ((m4 >> lane) & 1ull)
        outb[g_B4[j1] + base + __popcll(m4 & ((1ull << lane) - 1ull))] = l4v;
    }
    {
      int baseA = 0, baseB = 0, totalA = 0;
#pragma unroll
      for (int i = 0; i < 8; ++i) {
        int w = W5i[i];
        totalA += w & 0xffff;
        if (i < wv) { baseA += w & 0xffff; baseB += w >> 16; }
      }
      int slotA = g_B5[j1] + baseA + exA;
      int slotB = g_B5[j1] + totalA + baseB + exB;
#pragma unroll
      for (int e = 0; e < 4; ++e)
        if ((fm5a >> e) & 1u) outb[slotA++] = l5a[e];
#pragma unroll
      for (int e = 0; e < 4; ++e)
        if ((fm5b >> e) & 1u) outb[slotB++] = l5b[e];
    }
  }
  __syncthreads();   // barrier 3: A5 visible

  // ---- level 6: rank-driven eval, coalesced stores ----
  float* __restrict__ outr = outb + 7764 + r0;
  for (int i = tid; i < cnt; i += 512) {
    const int pl = PL[i];
    float v = S6j[pl]
            + sm[L_A5 + (pl >> 3)] * sm[L_S1 + (pl & 7)]
            + sm[L_A4 + (pl >> 6)] * sm[L_S2 + (pl & 63)]
            + sm[L_A3 + (pl >> 9)] * sm[L_S3 + (pl & 511)]
            + sm[L_A2 + (pl >> 12)] * S4g[pl & 4095]
            + c2p1 * S5g[pl];
    outr[i] = v;
  }
}

// ---------- launch ----------
// d_ws: pos16[43596] u16 (~85 KB)

extern "C" void kernel_launch(void* const* d_in, const int* in_sizes, int n_in,
                              void* d_out, int out_size, void* d_ws, size_t ws_size,
                              hipStream_t stream) {
  const float* sig = (const float*)d_in[0];
  float* out = (float*)d_out;
  u16* pos16 = (u16*)d_ws;

  lyndon_prep<<<7, 1024, 0, stream>>>(pos16);
  logsig_fused<<<1024, 512, 0, stream>>>(sig, pos16, out);
}